// Round 3
// baseline (1462.396 us; speedup 1.0000x reference)
//
#include <hip/hip_runtime.h>
#include <hip/hip_cooperative_groups.h>
#include <math.h>

#define H 1024
#define V 50257
#define L 12
#define GRID 1024  // == H; 4 blocks/CU at 256 thr

namespace cg = cooperative_groups;

// ws layout (fp32 elements)
#define OFF_EMB    0              // 1024 (contiguous with OFF_ATTN -> concat for phase 2)
#define OFF_ATTN   1024           // 1024
#define OFF_X      2048           // 1024
#define OFF_H0     3072           // 1024
#define OFF_H      4096           // 1024
#define OFF_LOGITS 5120           // 50257
#define OFF_SUM    (5120 + 50260) // 1 (sum-of-exp accumulator)

__device__ __forceinline__ float dot4(float4 a, float4 b) {
    return a.x * b.x + a.y * b.y + a.z * b.z + a.w * b.w;
}

__device__ __forceinline__ float wave_red(float s) {
    for (int o = 32; o > 0; o >>= 1) s += __shfl_down(s, o);
    return s;
}

__global__ __launch_bounds__(256, 4) void fused_decoder(
    const int* __restrict__ tok_p, const float* __restrict__ hidden,
    const float* __restrict__ enc, const float* __restrict__ emb,
    const float* __restrict__ attn_W, const float* __restrict__ attn_b,
    const float* __restrict__ comb_W, const float* __restrict__ comb_b,
    const float* __restrict__ Wih, const float* __restrict__ Whh,
    const float* __restrict__ bih, const float* __restrict__ bhh,
    const float* __restrict__ out_W, const float* __restrict__ out_b,
    float* __restrict__ ws, float* __restrict__ out)
{
    cg::grid_group grid = cg::this_grid();
    __shared__ float att_in[2 * H];
    __shared__ float red[4];
    __shared__ float wsm[L];
    __shared__ float bc;
    const int t = threadIdx.x;
    const int wave = t >> 6;
    const int lane = t & 63;

    // ---- Phase 1: embedding, attention softmax, attn_applied (block 0 only) ----
    if (blockIdx.x == 0) {
        const int tok = tok_p[0];
        const float* erow = emb + (size_t)tok * H;
        for (int j = t; j < H; j += 256) {
            float e  = erow[j];
            float h0 = hidden[j];
            att_in[j]       = e;
            att_in[H + j]   = h0;
            ws[OFF_EMB + j] = e;
            ws[OFF_H0 + j]  = h0;
        }
        if (t == 0) ws[OFF_SUM] = 0.f;  // ws is poisoned 0xAA each call
        __syncthreads();
        for (int l = 0; l < L; ++l) {
            float p = 0.f;
            const float* wr = attn_W + l * 2 * H;
            for (int j = t; j < 2 * H; j += 256) p += att_in[j] * wr[j];
            p = wave_red(p);
            if (lane == 0) red[wave] = p;
            __syncthreads();
            if (t == 0) wsm[l] = red[0] + red[1] + red[2] + red[3] + attn_b[l];
            __syncthreads();
        }
        if (t == 0) {
            float m = wsm[0];
            for (int l = 1; l < L; ++l) m = fmaxf(m, wsm[l]);
            float s = 0.f;
            for (int l = 0; l < L; ++l) { wsm[l] = expf(wsm[l] - m); s += wsm[l]; }
            float inv = 1.f / s;
            for (int l = 0; l < L; ++l) {
                wsm[l] *= inv;
                out[V + H + l] = wsm[l];  // attn_weights output
            }
        }
        __syncthreads();
        for (int hh = t; hh < H; hh += 256) {
            float a = 0.f;
            for (int l = 0; l < L; ++l) a += wsm[l] * enc[l * H + hh];
            ws[OFF_ATTN + hh] = a;
        }
    }
    __threadfence();
    grid.sync();
    __threadfence();

    // ---- Phase 2: x = relu([emb, attn] @ comb_W.T + comb_b), one row per block ----
    {
        const int row = blockIdx.x;  // GRID == H
        const float4* Wr = (const float4*)(comb_W + (size_t)row * 2 * H);
        const float4* vv = (const float4*)(ws + OFF_EMB);
        float s = dot4(Wr[t], vv[t]) + dot4(Wr[t + 256], vv[t + 256]);
        s = wave_red(s);
        if (lane == 0) red[wave] = s;
        __syncthreads();
        if (t == 0)
            ws[OFF_X + row] = fmaxf(red[0] + red[1] + red[2] + red[3] + comb_b[row], 0.f);
    }
    __threadfence();
    grid.sync();
    __threadfence();

    // ---- Phase 3: h = tanh(x @ Wih.T + bih + h0 @ Whh.T + bhh), one row per block ----
    {
        const int row = blockIdx.x;
        const float4* Wi = (const float4*)(Wih + (size_t)row * H);
        const float4* Wh = (const float4*)(Whh + (size_t)row * H);
        const float4* xv = (const float4*)(ws + OFF_X);
        const float4* hv = (const float4*)(ws + OFF_H0);
        float s = dot4(Wi[t], xv[t]) + dot4(Wh[t], hv[t]);
        s = wave_red(s);
        if (lane == 0) red[wave] = s;
        __syncthreads();
        if (t == 0) {
            float h = tanhf(red[0] + red[1] + red[2] + red[3] + bih[row] + bhh[row]);
            ws[OFF_H + row] = h;
            out[V + row] = h;  // h_new output
        }
        __syncthreads();  // protect red[] before phase 4 reuse
    }
    __threadfence();
    grid.sync();
    __threadfence();

    // ---- Phase 4: logits = h @ out_W.T + out_b; per-block partial sum(exp) ----
    // |logit| <~ 5 (h in [-1,1], W ~ N(0, .02^2)) so exp w/o max-subtract is fp32-safe.
    {
        float esum = 0.f;
        const float* hvec = ws + OFF_H;
        for (int row = blockIdx.x * 4 + wave; row < V; row += GRID * 4) {
            const float4* Wr = (const float4*)(out_W + (size_t)row * H);
            const float4* hv = (const float4*)hvec;
            float s = dot4(Wr[lane], hv[lane]) + dot4(Wr[lane + 64], hv[lane + 64])
                    + dot4(Wr[lane + 128], hv[lane + 128]) + dot4(Wr[lane + 192], hv[lane + 192]);
            s = wave_red(s);
            if (lane == 0) {
                float d = s + out_b[row];
                ws[OFF_LOGITS + row] = d;
                esum += expf(d);
            }
        }
        if (lane == 0) red[wave] = esum;
        __syncthreads();
        if (t == 0)
            atomicAdd(ws + OFF_SUM, red[0] + red[1] + red[2] + red[3]);
    }
    __threadfence();
    grid.sync();
    __threadfence();

    // ---- Phase 5: logp = logits - log(sum_exp) ----
    {
        if (t == 0) {
            float se = __hip_atomic_load(ws + OFF_SUM, __ATOMIC_RELAXED,
                                         __HIP_MEMORY_SCOPE_AGENT);
            bc = logf(se);
        }
        __syncthreads();
        const float lse = bc;
        const int idx = blockIdx.x * 256 + t;
        if (idx < V) out[idx] = ws[OFF_LOGITS + idx] - lse;
    }
}

extern "C" void kernel_launch(void* const* d_in, const int* in_sizes, int n_in,
                              void* d_out, int out_size, void* d_ws, size_t ws_size,
                              hipStream_t stream) {
    const int*   tok    = (const int*)d_in[0];
    const float* hidden = (const float*)d_in[1];
    const float* enc    = (const float*)d_in[2];
    const float* emb    = (const float*)d_in[3];
    const float* attn_W = (const float*)d_in[4];
    const float* attn_b = (const float*)d_in[5];
    const float* comb_W = (const float*)d_in[6];
    const float* comb_b = (const float*)d_in[7];
    const float* Wih    = (const float*)d_in[8];
    const float* Whh    = (const float*)d_in[9];
    const float* bih    = (const float*)d_in[10];
    const float* bhh    = (const float*)d_in[11];
    const float* out_W  = (const float*)d_in[12];
    const float* out_b  = (const float*)d_in[13];
    float* ws  = (float*)d_ws;
    float* out = (float*)d_out;

    void* args[] = { (void*)&tok, (void*)&hidden, (void*)&enc, (void*)&emb,
                     (void*)&attn_W, (void*)&attn_b, (void*)&comb_W, (void*)&comb_b,
                     (void*)&Wih, (void*)&Whh, (void*)&bih, (void*)&bhh,
                     (void*)&out_W, (void*)&out_b, (void*)&ws, (void*)&out };
    hipLaunchCooperativeKernel((void*)fused_decoder, dim3(GRID), dim3(256),
                               args, 0, stream);
}

// Round 4
// 407.033 us; speedup vs baseline: 3.5928x; 3.5928x over previous
//
#include <hip/hip_runtime.h>
#include <math.h>

#define H 1024
#define V 50257
#define L 12

// ws layout (fp32 elements)
#define OFF_EMB    0              // 1024 (contiguous with OFF_ATTN -> concat for k2)
#define OFF_ATTN   1024           // 1024
#define OFF_X      2048           // 1024
#define OFF_H0     3072           // 1024
#define OFF_H      4096           // 1024
#define OFF_LOGITS 5120           // 50257 (ends at 55377)
#define OFF_PART   56384          // NB4 per-block exp-sum partials
#define NB4        4096           // k4 grid

__device__ __forceinline__ float dot4(float4 a, float4 b) {
    return a.x * b.x + a.y * b.y + a.z * b.z + a.w * b.w;
}

__device__ __forceinline__ float wave_red(float s) {
    for (int o = 32; o > 0; o >>= 1) s += __shfl_down(s, o);
    return s;
}

// K1: embedding, attention softmax, attn_applied. One 1024-thread block.
// Wave l (l<12) computes attention logit l with 8-deep float4 ILP.
__global__ __launch_bounds__(1024) void k1_attn(
    const int* __restrict__ tok_p, const float* __restrict__ hidden,
    const float* __restrict__ enc, const float* __restrict__ emb,
    const float* __restrict__ attn_W, const float* __restrict__ attn_b,
    float* __restrict__ ws, float* __restrict__ out)
{
    __shared__ float4 att_in4[512];   // [emb | h0], 2048 floats
    __shared__ float wsm[L];
    float* att_in = (float*)att_in4;
    const int t = threadIdx.x;
    const int wave = t >> 6;
    const int lane = t & 63;
    const int tok = tok_p[0];

    float e  = emb[(size_t)tok * H + t];
    float h0 = hidden[t];
    att_in[t]       = e;
    att_in[H + t]   = h0;
    ws[OFF_EMB + t] = e;
    ws[OFF_H0 + t]  = h0;
    __syncthreads();

    if (wave < L) {
        const float4* wr = (const float4*)(attn_W + (size_t)wave * 2 * H);
        float s = 0.f;
#pragma unroll
        for (int i = 0; i < 8; ++i)
            s += dot4(wr[lane + 64 * i], att_in4[lane + 64 * i]);
        s = wave_red(s);
        if (lane == 0) wsm[wave] = s + attn_b[wave];
    }
    __syncthreads();

    if (t == 0) {
        float m = wsm[0];
        for (int l = 1; l < L; ++l) m = fmaxf(m, wsm[l]);
        float s = 0.f;
        for (int l = 0; l < L; ++l) { wsm[l] = expf(wsm[l] - m); s += wsm[l]; }
        float inv = 1.f / s;
        for (int l = 0; l < L; ++l) {
            wsm[l] *= inv;
            out[V + H + l] = wsm[l];  // attn_weights output
        }
    }
    __syncthreads();

    float a = 0.f;
#pragma unroll
    for (int l = 0; l < L; ++l) a += wsm[l] * enc[l * H + t];
    ws[OFF_ATTN + t] = a;
}

// K2: x = relu([emb, attn] @ comb_W.T + comb_b). Wave per row, 8-deep ILP.
__global__ __launch_bounds__(256) void k2_combine(
    const float* __restrict__ comb_W, const float* __restrict__ comb_b,
    float* __restrict__ ws)
{
    const int wave = threadIdx.x >> 6;
    const int lane = threadIdx.x & 63;
    const int row = blockIdx.x * 4 + wave;
    const float4* Wr = (const float4*)(comb_W + (size_t)row * 2 * H);
    const float4* vv = (const float4*)(ws + OFF_EMB);
    float s = 0.f;
#pragma unroll
    for (int i = 0; i < 8; ++i)
        s += dot4(Wr[lane + 64 * i], vv[lane + 64 * i]);
    s = wave_red(s);
    if (lane == 0) ws[OFF_X + row] = fmaxf(s + comb_b[row], 0.f);
}

// K3: h = tanh(x @ Wih.T + bih + h0 @ Whh.T + bhh). Wave per row.
__global__ __launch_bounds__(256) void k3_rnn(
    const float* __restrict__ Wih, const float* __restrict__ Whh,
    const float* __restrict__ bih, const float* __restrict__ bhh,
    float* __restrict__ ws, float* __restrict__ out)
{
    const int wave = threadIdx.x >> 6;
    const int lane = threadIdx.x & 63;
    const int row = blockIdx.x * 4 + wave;
    const float4* Wi = (const float4*)(Wih + (size_t)row * H);
    const float4* Wh = (const float4*)(Whh + (size_t)row * H);
    const float4* xv = (const float4*)(ws + OFF_X);
    const float4* hv = (const float4*)(ws + OFF_H0);
    float s = 0.f;
#pragma unroll
    for (int i = 0; i < 4; ++i)
        s += dot4(Wi[lane + 64 * i], xv[lane + 64 * i])
           + dot4(Wh[lane + 64 * i], hv[lane + 64 * i]);
    s = wave_red(s);
    if (lane == 0) {
        float h = tanhf(s + bih[row] + bhh[row]);
        ws[OFF_H + row] = h;
        out[V + row] = h;  // h_new output
    }
}

// K4: logits = h @ out_W.T + out_b; per-block exp-sum partial (atomic-free).
// h fragment hoisted into 16 VGPRs (identical across rows).
// |logit| <~ 5 so exp without max-subtraction is fp32-safe.
__global__ __launch_bounds__(256) void k4_outproj(
    const float* __restrict__ out_W, const float* __restrict__ out_b,
    float* __restrict__ ws)
{
    __shared__ float red[4];
    const int wave = threadIdx.x >> 6;
    const int lane = threadIdx.x & 63;
    const float4* hv = (const float4*)(ws + OFF_H);
    const float4 h0 = hv[lane];
    const float4 h1 = hv[lane + 64];
    const float4 h2 = hv[lane + 128];
    const float4 h3 = hv[lane + 192];
    float esum = 0.f;
    for (int row = blockIdx.x * 4 + wave; row < V; row += NB4 * 4) {
        const float4* Wr = (const float4*)(out_W + (size_t)row * H);
        float s = dot4(Wr[lane], h0) + dot4(Wr[lane + 64], h1)
                + dot4(Wr[lane + 128], h2) + dot4(Wr[lane + 192], h3);
        s = wave_red(s);
        if (lane == 0) {
            float d = s + out_b[row];
            ws[OFF_LOGITS + row] = d;
            esum += expf(d);
        }
    }
    if (lane == 0) red[wave] = esum;
    __syncthreads();
    if (threadIdx.x == 0)
        ws[OFF_PART + blockIdx.x] = red[0] + red[1] + red[2] + red[3];
}

// K5: each block redundantly reduces the NB4 partials (L2-resident, 16 KB),
// then writes logp = logits - log(sum_exp).
__global__ __launch_bounds__(256) void k5_norm(
    const float* __restrict__ ws, float* __restrict__ out)
{
    __shared__ float red[4];
    __shared__ float sbc;
    const int t = threadIdx.x;
    const int wave = t >> 6;
    const int lane = t & 63;
    float s = 0.f;
    for (int i = t; i < NB4; i += 256) s += ws[OFF_PART + i];
    s = wave_red(s);
    if (lane == 0) red[wave] = s;
    __syncthreads();
    if (t == 0) sbc = logf(red[0] + red[1] + red[2] + red[3]);
    __syncthreads();
    const float lse = sbc;
    const int idx = blockIdx.x * 256 + t;
    if (idx < V) out[idx] = ws[OFF_LOGITS + idx] - lse;
}

extern "C" void kernel_launch(void* const* d_in, const int* in_sizes, int n_in,
                              void* d_out, int out_size, void* d_ws, size_t ws_size,
                              hipStream_t stream) {
    const int*   tok    = (const int*)d_in[0];
    const float* hidden = (const float*)d_in[1];
    const float* enc    = (const float*)d_in[2];
    const float* emb    = (const float*)d_in[3];
    const float* attn_W = (const float*)d_in[4];
    const float* attn_b = (const float*)d_in[5];
    const float* comb_W = (const float*)d_in[6];
    const float* comb_b = (const float*)d_in[7];
    const float* Wih    = (const float*)d_in[8];
    const float* Whh    = (const float*)d_in[9];
    const float* bih    = (const float*)d_in[10];
    const float* bhh    = (const float*)d_in[11];
    const float* out_W  = (const float*)d_in[12];
    const float* out_b  = (const float*)d_in[13];
    float* ws  = (float*)d_ws;
    float* out = (float*)d_out;

    k1_attn   <<<1,                1024, 0, stream>>>(tok, hidden, enc, emb, attn_W, attn_b, ws, out);
    k2_combine<<<H / 4,            256,  0, stream>>>(comb_W, comb_b, ws);
    k3_rnn    <<<H / 4,            256,  0, stream>>>(Wih, Whh, bih, bhh, ws, out);
    k4_outproj<<<NB4,              256,  0, stream>>>(out_W, out_b, ws);
    k5_norm   <<<(V + 255) / 256,  256,  0, stream>>>(ws, out);
}